// Round 1
// 12785.533 us; speedup vs baseline: 1.0158x; 1.0158x over previous
//
#include <hip/hip_runtime.h>
#include <math.h>

// Problem constants
#define TX 64
#define BN 64
#define TY 32
#define EE 256
#define HH 512
#define H3 1536
#define KYV 32000

typedef __attribute__((ext_vector_type(8))) short bf16x8;
typedef __attribute__((ext_vector_type(4))) float f32x4;

__device__ __forceinline__ float4 ldf4(const float* p) { return *(const float4*)p; }
__device__ __forceinline__ float sigf(float x) { return 1.f / (1.f + expf(-x)); }

// round-to-nearest-even fp32 -> bf16 bits
__device__ __forceinline__ short f2bf(float x) {
    unsigned u = __float_as_uint(x);
    unsigned r = (u + 0x7fffu + ((u >> 16) & 1u)) >> 16;
    return (short)r;
}
__device__ __forceinline__ float bf2f(short h) {
    return __uint_as_float(((unsigned)(unsigned short)h) << 16);
}

// ---------------------------------------------------------------------------
// Generic NT GEMM (fp32): C[M x N] = A[M x K] * B[N x K]^T (+bias), optional
// A row gather. Tiles 64x64, K-tile 32. M,N % 64 == 0, K % 32 == 0.
// ---------------------------------------------------------------------------
__global__ __launch_bounds__(256) void gemm_nt_kernel(
    const float* __restrict__ Abase, const int* __restrict__ gather, int lda,
    const float* __restrict__ Bbase, int ldb, int bofs,
    const float* __restrict__ bias, float* __restrict__ C, int ldc, int K)
{
    __shared__ float As[32][68];
    __shared__ float Bs[32][68];
    const int tid = threadIdx.x;
    const int n0 = blockIdx.x * 64;
    const int m0 = blockIdx.y * 64;
    const int tx = tid & 15, ty = tid >> 4;
    const int li = tid >> 2, lk = (tid & 3) * 8;
    float acc[4][4] = {};
    const float* arow = gather ? (Abase + (size_t)gather[m0 + li] * lda)
                               : (Abase + (size_t)(m0 + li) * lda);
    const float* brow = Bbase + (size_t)(n0 + li) * ldb + bofs;
    for (int kt = 0; kt < K; kt += 32) {
        float4 a0 = ldf4(arow + kt + lk);
        float4 a1 = ldf4(arow + kt + lk + 4);
        float4 b0 = ldf4(brow + kt + lk);
        float4 b1 = ldf4(brow + kt + lk + 4);
        __syncthreads();
        As[lk+0][li]=a0.x; As[lk+1][li]=a0.y; As[lk+2][li]=a0.z; As[lk+3][li]=a0.w;
        As[lk+4][li]=a1.x; As[lk+5][li]=a1.y; As[lk+6][li]=a1.z; As[lk+7][li]=a1.w;
        Bs[lk+0][li]=b0.x; Bs[lk+1][li]=b0.y; Bs[lk+2][li]=b0.z; Bs[lk+3][li]=b0.w;
        Bs[lk+4][li]=b1.x; Bs[lk+5][li]=b1.y; Bs[lk+6][li]=b1.z; Bs[lk+7][li]=b1.w;
        __syncthreads();
        #pragma unroll
        for (int k = 0; k < 32; ++k) {
            float4 av = *(const float4*)&As[k][ty*4];
            float4 bv = *(const float4*)&Bs[k][tx*4];
            acc[0][0] += av.x*bv.x; acc[0][1] += av.x*bv.y; acc[0][2] += av.x*bv.z; acc[0][3] += av.x*bv.w;
            acc[1][0] += av.y*bv.x; acc[1][1] += av.y*bv.y; acc[1][2] += av.y*bv.z; acc[1][3] += av.y*bv.w;
            acc[2][0] += av.z*bv.x; acc[2][1] += av.z*bv.y; acc[2][2] += av.z*bv.z; acc[2][3] += av.z*bv.w;
            acc[3][0] += av.w*bv.x; acc[3][1] += av.w*bv.y; acc[3][2] += av.w*bv.z; acc[3][3] += av.w*bv.w;
        }
    }
    #pragma unroll
    for (int ii = 0; ii < 4; ++ii) {
        int r = m0 + ty*4 + ii;
        #pragma unroll
        for (int jj = 0; jj < 4; ++jj) {
            int c = n0 + tx*4 + jj;
            float v = acc[ii][jj];
            if (bias) v += bias[c];
            C[(size_t)r*ldc + c] = v;
        }
    }
}

// ---------------------------------------------------------------------------
// Encoder recurrent step.
// ---------------------------------------------------------------------------
__global__ __launch_bounds__(256) void enc_step_kernel(
    const float* __restrict__ GI_f, const float* __restrict__ GI_b,
    const float* __restrict__ Whh_f, const float* __restrict__ bhh_f,
    const float* __restrict__ Whh_b, const float* __restrict__ bhh_b,
    const float* __restrict__ hf_in, float* __restrict__ hf_out,
    const float* __restrict__ hb_in, float* __restrict__ hb_out,
    float* __restrict__ enc_out, int t)
{
    const int blk = blockIdx.x;
    const int dir = blk >> 7;
    const int r = blk & 127;
    const int cg = r >> 1;
    const int bh = r & 1;
    const int sub = threadIdx.x >> 5;
    const int b = bh*32 + (threadIdx.x & 31);
    const int col = cg*8 + sub;

    const float* GI = dir ? GI_b : GI_f;
    const float* W  = dir ? Whh_b : Whh_f;
    const float* bh_v = dir ? bhh_b : bhh_f;
    const float* hin  = dir ? hb_in : hf_in;
    float* hout = dir ? hb_out : hf_out;
    const int tstep = dir ? (TX-1-t) : t;

    const float* hrow = hin + b*HH;
    const float* wr = W + (size_t)col*HH;
    const float* wz = W + (size_t)(HH + col)*HH;
    const float* wn = W + (size_t)(2*HH + col)*HH;
    float ar = 0.f, az = 0.f, an = 0.f;
    for (int k = 0; k < HH; k += 4) {
        float4 hv = ldf4(hrow + k);
        float4 A = ldf4(wr + k), Z = ldf4(wz + k), N = ldf4(wn + k);
        ar += hv.x*A.x + hv.y*A.y + hv.z*A.z + hv.w*A.w;
        az += hv.x*Z.x + hv.y*Z.y + hv.z*Z.z + hv.w*Z.w;
        an += hv.x*N.x + hv.y*N.y + hv.z*N.z + hv.w*N.w;
    }
    size_t gbase = ((size_t)tstep*BN + b) * H3;
    float ir = GI[gbase + col];
    float iz = GI[gbase + HH + col];
    float inn = GI[gbase + 2*HH + col];
    float rr = sigf(ir + ar + bh_v[col]);
    float zz = sigf(iz + az + bh_v[HH + col]);
    float nn = tanhf(inn + rr*(an + bh_v[2*HH + col]));
    float hold = hrow[col];
    float h2 = (1.f - zz)*nn + zz*hold;
    hout[b*HH + col] = h2;
    enc_out[((size_t)tstep*BN + b)*(2*HH) + dir*HH + col] = h2;
}

// ---------------------------------------------------------------------------
// Decoder init: hidden = tanh(h_b_final @ W_init.T + b_init); tok = 1
// ---------------------------------------------------------------------------
__global__ __launch_bounds__(256) void dec_init_kernel(
    const float* __restrict__ hbf, const float* __restrict__ Wi,
    const float* __restrict__ bi, float* __restrict__ hdec, int* __restrict__ tok)
{
    const int b = blockIdx.x, tid = threadIdx.x;
    const float* hr = hbf + b*HH;
    for (int n = tid; n < HH; n += 256) {
        float acc = bi[n];
        const float* w = Wi + (size_t)n*HH;
        for (int k = 0; k < HH; k += 4) {
            float4 hv = ldf4(hr + k), wv = ldf4(w + k);
            acc += hv.x*wv.x + hv.y*wv.y + hv.z*wv.z + hv.w*wv.w;
        }
        hdec[b*HH + n] = tanhf(acc);
    }
    if (b == 0 && tid < 64) tok[tid] = 1;
}

// ---------------------------------------------------------------------------
// Attention + context. Also emits bf16 hi/lo of ctx into A[:,512:1536].
// ---------------------------------------------------------------------------
__global__ __launch_bounds__(256) void attn_kernel(
    const float* __restrict__ h, const float* __restrict__ P,
    const float* __restrict__ enc, const float* __restrict__ Wa1,
    const float* __restrict__ ba1, const float* __restrict__ Wa2,
    const float* __restrict__ ba2, float* __restrict__ ctx,
    short* __restrict__ Ahi, short* __restrict__ Alo)
{
    __shared__ float hs[HH];
    __shared__ float qs[HH];
    __shared__ float ss[TX];
    __shared__ float ww[TX];
    const int b = blockIdx.x, tid = threadIdx.x;
    hs[tid] = h[b*HH + tid];
    hs[tid + 256] = h[b*HH + 256 + tid];
    __syncthreads();
    for (int n = tid; n < HH; n += 256) {
        float acc = ba1[n];
        const float* w = Wa1 + (size_t)n*H3;
        for (int k = 0; k < HH; k += 4) {
            float4 wv = ldf4(w + k);
            acc += hs[k]*wv.x + hs[k+1]*wv.y + hs[k+2]*wv.z + hs[k+3]*wv.w;
        }
        qs[n] = acc;
    }
    __syncthreads();
    {
        const int t = tid >> 2, part = tid & 3;
        const float* p = P + ((size_t)t*BN + b)*HH + part*128;
        const float* w2 = Wa2 + part*128;
        const float* q = qs + part*128;
        float acc = 0.f;
        for (int k = 0; k < 128; k += 4) {
            float4 pv = ldf4(p + k), wv = ldf4(w2 + k);
            acc += wv.x*tanhf(q[k+0] + pv.x);
            acc += wv.y*tanhf(q[k+1] + pv.y);
            acc += wv.z*tanhf(q[k+2] + pv.z);
            acc += wv.w*tanhf(q[k+3] + pv.w);
        }
        acc += __shfl_xor(acc, 1);
        acc += __shfl_xor(acc, 2);
        if (part == 0) ss[t] = acc + ba2[0];
    }
    __syncthreads();
    if (tid < 64) {
        float v = ss[tid];
        float m = v;
        for (int off = 32; off; off >>= 1) m = fmaxf(m, __shfl_xor(m, off));
        float e = expf(v - m);
        float sm = e;
        for (int off = 32; off; off >>= 1) sm += __shfl_xor(sm, off);
        ww[tid] = e / sm;
    }
    __syncthreads();
    for (int c = tid; c < 2*HH; c += 256) {
        float acc = 0.f;
        #pragma unroll 4
        for (int t2 = 0; t2 < TX; ++t2)
            acc += ww[t2] * enc[((size_t)t2*BN + b)*(2*HH) + c];
        ctx[b*(2*HH) + c] = acc;
        short hi = f2bf(acc);
        Ahi[(size_t)b*H3 + HH + c] = hi;
        Alo[(size_t)b*H3 + HH + c] = f2bf(acc - bf2f(hi));
    }
}

// ---------------------------------------------------------------------------
// Decoder GRU step. Also emits bf16 hi/lo of h2 into A[:,0:512].
// ---------------------------------------------------------------------------
__global__ __launch_bounds__(256) void dec_gru_kernel(
    const float* __restrict__ demb, const int* __restrict__ tok,
    const float* __restrict__ ctx, const float* __restrict__ h,
    const float* __restrict__ Wih, const float* __restrict__ Whh,
    const float* __restrict__ bih, const float* __restrict__ bhh,
    float* __restrict__ hout, short* __restrict__ Ahi, short* __restrict__ Alo)
{
    const int col = blockIdx.x*4 + (threadIdx.x >> 6);
    const int b = threadIdx.x & 63;
    const float* emb = demb + (size_t)tok[b]*EE;
    const float* cr = ctx + b*(2*HH);
    const float* hr = h + b*HH;
    const float* wri = Wih + (size_t)col*1280;
    const float* wzi = Wih + (size_t)(HH + col)*1280;
    const float* wni = Wih + (size_t)(2*HH + col)*1280;
    float ir = 0.f, iz = 0.f, inn = 0.f;
    for (int k = 0; k < EE; k += 4) {
        float4 e = ldf4(emb + k);
        float4 A = ldf4(wri + k), Z = ldf4(wzi + k), N = ldf4(wni + k);
        ir  += e.x*A.x + e.y*A.y + e.z*A.z + e.w*A.w;
        iz  += e.x*Z.x + e.y*Z.y + e.z*Z.z + e.w*Z.w;
        inn += e.x*N.x + e.y*N.y + e.z*N.z + e.w*N.w;
    }
    for (int k = 0; k < 2*HH; k += 4) {
        float4 c = ldf4(cr + k);
        float4 A = ldf4(wri + EE + k), Z = ldf4(wzi + EE + k), N = ldf4(wni + EE + k);
        ir  += c.x*A.x + c.y*A.y + c.z*A.z + c.w*A.w;
        iz  += c.x*Z.x + c.y*Z.y + c.z*Z.z + c.w*Z.w;
        inn += c.x*N.x + c.y*N.y + c.z*N.z + c.w*N.w;
    }
    const float* wrh = Whh + (size_t)col*HH;
    const float* wzh = Whh + (size_t)(HH + col)*HH;
    const float* wnh = Whh + (size_t)(2*HH + col)*HH;
    float hrr = 0.f, hzz = 0.f, hnn = 0.f;
    for (int k = 0; k < HH; k += 4) {
        float4 hv = ldf4(hr + k);
        float4 A = ldf4(wrh + k), Z = ldf4(wzh + k), N = ldf4(wnh + k);
        hrr += hv.x*A.x + hv.y*A.y + hv.z*A.z + hv.w*A.w;
        hzz += hv.x*Z.x + hv.y*Z.y + hv.z*Z.z + hv.w*Z.w;
        hnn += hv.x*N.x + hv.y*N.y + hv.z*N.z + hv.w*N.w;
    }
    float rr = sigf(ir + bih[col] + hrr + bhh[col]);
    float zz = sigf(iz + bih[HH + col] + hzz + bhh[HH + col]);
    float nn = tanhf(inn + bih[2*HH + col] + rr*(hnn + bhh[2*HH + col]));
    float hv0 = hr[col];
    float h2 = (1.f - zz)*nn + zz*hv0;
    hout[b*HH + col] = h2;
    short hi = f2bf(h2);
    Ahi[(size_t)b*H3 + col] = hi;
    Alo[(size_t)b*H3 + col] = f2bf(h2 - bf2f(hi));
}

// ---------------------------------------------------------------------------
// MFMA logits with ON-THE-FLY fp32 -> bf16 hi/lo split of W (no workspace
// W planes needed; traffic identical to two precomputed bf16 planes:
// 32 B/lane/tile either way).
// out[b,n] = A[b,:] . W[n,:] + blsm[n], split-precision:
//   a*w ~= ah*wh + al*wh + ah*wl   (wh = trunc-to-bf16, wl = RNE(w - wh);
//   the lo plane absorbs the truncation exactly; dropped al*wl ~ 2^-17 rel)
// A,W row-major K=1536. Block = 4 waves; wave w handles A rows [16w,16w+16);
// block covers 64 N-cols. Grid = 500.
// MFMA 16x16x32: A frag A[m=lane&15][k=(lane>>4)*8+j]; B frag
// B[n=lane&15][k=(lane>>4)*8+j]; D: row=(lane>>4)*4+reg, col=lane&15.
// ---------------------------------------------------------------------------
__global__ __launch_bounds__(256) void logits_mfma_kernel(
    const short* __restrict__ Ahi, const short* __restrict__ Alo,
    const float* __restrict__ W, const float* __restrict__ blsm,
    float* __restrict__ outrow)
{
    const int wave = threadIdx.x >> 6;
    const int lane = threadIdx.x & 63;
    const int n0 = blockIdx.x * 64;
    const int m = lane & 15;
    const int q = lane >> 4;

    const short* arow_h = Ahi + (size_t)(wave*16 + m)*H3 + q*8;
    const short* arow_l = Alo + (size_t)(wave*16 + m)*H3 + q*8;
    const float* brow = W + (size_t)(n0 + m)*H3 + q*8;

    f32x4 acc[4] = {{0,0,0,0},{0,0,0,0},{0,0,0,0},{0,0,0,0}};
    for (int kt = 0; kt < H3; kt += 32) {
        bf16x8 ah = *(const bf16x8*)(arow_h + kt);
        bf16x8 al = *(const bf16x8*)(arow_l + kt);
        // load all 4 tiles' fp32 W chunks first (8 x float4), then convert+mfma
        float4 w0[4], w1[4];
        #pragma unroll
        for (int t = 0; t < 4; ++t) {
            const float* bp = brow + (size_t)(16*t)*H3 + kt;
            w0[t] = ldf4(bp);
            w1[t] = ldf4(bp + 4);
        }
        #pragma unroll
        for (int t = 0; t < 4; ++t) {
            float f0 = w0[t].x, f1 = w0[t].y, f2 = w0[t].z, f3 = w0[t].w;
            float f4 = w1[t].x, f5 = w1[t].y, f6 = w1[t].z, f7 = w1[t].w;
            bf16x8 bh, bl;
            {
                unsigned u, hu;
                u = __float_as_uint(f0); hu = u & 0xffff0000u; bh[0] = (short)(hu>>16); bl[0] = f2bf(f0 - __uint_as_float(hu));
                u = __float_as_uint(f1); hu = u & 0xffff0000u; bh[1] = (short)(hu>>16); bl[1] = f2bf(f1 - __uint_as_float(hu));
                u = __float_as_uint(f2); hu = u & 0xffff0000u; bh[2] = (short)(hu>>16); bl[2] = f2bf(f2 - __uint_as_float(hu));
                u = __float_as_uint(f3); hu = u & 0xffff0000u; bh[3] = (short)(hu>>16); bl[3] = f2bf(f3 - __uint_as_float(hu));
                u = __float_as_uint(f4); hu = u & 0xffff0000u; bh[4] = (short)(hu>>16); bl[4] = f2bf(f4 - __uint_as_float(hu));
                u = __float_as_uint(f5); hu = u & 0xffff0000u; bh[5] = (short)(hu>>16); bl[5] = f2bf(f5 - __uint_as_float(hu));
                u = __float_as_uint(f6); hu = u & 0xffff0000u; bh[6] = (short)(hu>>16); bl[6] = f2bf(f6 - __uint_as_float(hu));
                u = __float_as_uint(f7); hu = u & 0xffff0000u; bh[7] = (short)(hu>>16); bl[7] = f2bf(f7 - __uint_as_float(hu));
            }
            acc[t] = __builtin_amdgcn_mfma_f32_16x16x32_bf16(ah, bh, acc[t], 0, 0, 0);
            acc[t] = __builtin_amdgcn_mfma_f32_16x16x32_bf16(al, bh, acc[t], 0, 0, 0);
            acc[t] = __builtin_amdgcn_mfma_f32_16x16x32_bf16(ah, bl, acc[t], 0, 0, 0);
        }
    }
    const int row = wave*16 + q*4;
    #pragma unroll
    for (int r = 0; r < 4; ++r) {
        size_t ro = (size_t)(row + r)*KYV;
        outrow[ro + n0 +  0 + m] = acc[0][r] + blsm[n0 +  0 + m];
        outrow[ro + n0 + 16 + m] = acc[1][r] + blsm[n0 + 16 + m];
        outrow[ro + n0 + 32 + m] = acc[2][r] + blsm[n0 + 32 + m];
        outrow[ro + n0 + 48 + m] = acc[3][r] + blsm[n0 + 48 + m];
    }
}

// ---------------------------------------------------------------------------
// Fused per-row logsumexp + argmax + in-place (logits - lse) over 32000
// logits (float4 loads). 1 block/row; second pass re-reads the L2-hot row.
// ---------------------------------------------------------------------------
__global__ __launch_bounds__(256) void lse_argmax_sub_kernel(
    float* __restrict__ rows, int* __restrict__ tok)
{
    const int b = blockIdx.x, tid = threadIdx.x;
    float4* row4 = (float4*)(rows + (size_t)b*KYV);
    float m = -1e30f, s = 0.f; int bi = 0;
    for (int i = tid; i < KYV/4; i += 256) {
        float4 v = row4[i];
        if (v.x > m) { s = s*expf(m - v.x) + 1.f; m = v.x; bi = 4*i+0; } else s += expf(v.x - m);
        if (v.y > m) { s = s*expf(m - v.y) + 1.f; m = v.y; bi = 4*i+1; } else s += expf(v.y - m);
        if (v.z > m) { s = s*expf(m - v.z) + 1.f; m = v.z; bi = 4*i+2; } else s += expf(v.z - m);
        if (v.w > m) { s = s*expf(m - v.w) + 1.f; m = v.w; bi = 4*i+3; } else s += expf(v.w - m);
    }
    for (int off = 32; off; off >>= 1) {
        float m2 = __shfl_xor(m, off);
        float s2 = __shfl_xor(s, off);
        int i2 = __shfl_xor(bi, off);
        if (m2 > m || (m2 == m && i2 < bi)) { s = s2 + s*expf(m - m2); m = m2; bi = i2; }
        else s = s + s2*expf(m2 - m);
    }
    __shared__ float ms[4], ssh[4];
    __shared__ int is_[4];
    __shared__ float l_sh;
    const int wid = tid >> 6;
    if ((tid & 63) == 0) { ms[wid] = m; ssh[wid] = s; is_[wid] = bi; }
    __syncthreads();
    if (tid == 0) {
        for (int w = 1; w < 4; ++w) {
            float m2 = ms[w], s2 = ssh[w]; int i2 = is_[w];
            if (m2 > m || (m2 == m && i2 < bi)) { s = s2 + s*expf(m - m2); m = m2; bi = i2; }
            else s = s + s2*expf(m2 - m);
        }
        l_sh = m + logf(s);
        tok[b] = bi;
    }
    __syncthreads();
    const float l = l_sh;
    for (int i = tid; i < KYV/4; i += 256) {
        float4 v = row4[i];
        v.x -= l; v.y -= l; v.z -= l; v.w -= l;
        row4[i] = v;
    }
}

// ---------------------------------------------------------------------------
extern "C" void kernel_launch(void* const* d_in, const int* in_sizes, int n_in,
                              void* d_out, int out_size, void* d_ws, size_t ws_size,
                              hipStream_t stream)
{
    const int*   inputs  = (const int*)  d_in[0];
    const float* enc_emb = (const float*)d_in[2];
    const float* W_ih_f  = (const float*)d_in[3];
    const float* W_hh_f  = (const float*)d_in[4];
    const float* b_ih_f  = (const float*)d_in[5];
    const float* b_hh_f  = (const float*)d_in[6];
    const float* W_ih_b  = (const float*)d_in[7];
    const float* W_hh_b  = (const float*)d_in[8];
    const float* b_ih_b  = (const float*)d_in[9];
    const float* b_hh_b  = (const float*)d_in[10];
    const float* W_init  = (const float*)d_in[11];
    const float* b_init  = (const float*)d_in[12];
    const float* dec_emb = (const float*)d_in[13];
    const float* W_ih_d  = (const float*)d_in[14];
    const float* W_hh_d  = (const float*)d_in[15];
    const float* b_ih_d  = (const float*)d_in[16];
    const float* b_hh_d  = (const float*)d_in[17];
    const float* W_lsm   = (const float*)d_in[18];
    const float* b_lsm   = (const float*)d_in[19];
    const float* W_a1    = (const float*)d_in[20];
    const float* b_a1    = (const float*)d_in[21];
    const float* W_a2    = (const float*)d_in[22];
    const float* b_a2    = (const float*)d_in[23];

    float* ws = (float*)d_ws;
    float* GI_f   = ws;
    float* GI_b   = GI_f + (size_t)4096*1536;
    float* enc_out= GI_b + (size_t)4096*1536;
    float* P_enc  = enc_out + (size_t)4096*1024;
    float* hf     = P_enc + (size_t)4096*512;
    float* hb     = hf + 2*BN*HH;
    float* hdec   = hb + 2*BN*HH;
    float* ctx    = hdec + 2*BN*HH;
    float* lse    = ctx + BN*2*HH;    // kept for layout stability (unused)
    int*   tok    = (int*)(lse + BN);
    // bf16 A planes (16B aligned: offset above is a multiple of 16 bytes)
    short* A_hi = (short*)(tok + 64);
    short* A_lo = A_hi + (size_t)BN*H3;

    hipMemsetAsync(hf, 0, BN*HH*sizeof(float), stream);
    hipMemsetAsync(hb, 0, BN*HH*sizeof(float), stream);

    // Input projections for both encoder directions
    dim3 g1(H3/64, (TX*BN)/64);
    gemm_nt_kernel<<<g1, 256, 0, stream>>>(enc_emb, inputs, EE, W_ih_f, EE, 0,
                                           b_ih_f, GI_f, H3, EE);
    gemm_nt_kernel<<<g1, 256, 0, stream>>>(enc_emb, inputs, EE, W_ih_b, EE, 0,
                                           b_ih_b, GI_b, H3, EE);

    for (int t = 0; t < TX; ++t) {
        const float* hfi = hf + (t & 1)*BN*HH;
        float*       hfo = hf + ((t + 1) & 1)*BN*HH;
        const float* hbi = hb + (t & 1)*BN*HH;
        float*       hbo = hb + ((t + 1) & 1)*BN*HH;
        enc_step_kernel<<<256, 256, 0, stream>>>(GI_f, GI_b, W_hh_f, b_hh_f,
                                                 W_hh_b, b_hh_b, hfi, hfo, hbi, hbo,
                                                 enc_out, t);
    }

    dim3 g2(HH/64, (TX*BN)/64);
    gemm_nt_kernel<<<g2, 256, 0, stream>>>(enc_out, nullptr, 2*HH, W_a1, H3, HH,
                                           nullptr, P_enc, HH, 2*HH);

    dec_init_kernel<<<BN, 256, 0, stream>>>(hb, W_init, b_init, hdec, tok);

    float* out = (float*)d_out;
    for (int s = 0; s < TY; ++s) {
        float* h_cur = hdec + (s & 1)*BN*HH;
        float* h_nxt = hdec + ((s + 1) & 1)*BN*HH;
        attn_kernel<<<BN, 256, 0, stream>>>(h_cur, P_enc, enc_out, W_a1, b_a1,
                                            W_a2, b_a2, ctx, A_hi, A_lo);
        dec_gru_kernel<<<128, 256, 0, stream>>>(dec_emb, tok, ctx, h_cur,
                                                W_ih_d, W_hh_d, b_ih_d, b_hh_d,
                                                h_nxt, A_hi, A_lo);
        float* lrow = out + (size_t)s*BN*KYV;
        logits_mfma_kernel<<<KYV/64, 256, 0, stream>>>(A_hi, A_lo, W_lsm,
                                                       b_lsm, lrow);
        lse_argmax_sub_kernel<<<BN, 256, 0, stream>>>(lrow, tok);
    }
}